// Round 2
// baseline (556.389 us; speedup 1.0000x reference)
//
#include <hip/hip_runtime.h>
#include <cstddef>

// Vanilla tanh-RNN: B=4096, T=2048, I=4, H=20, then Linear(20->4) on h_last.
//
// Round-2 design: DPP-only recurrence (no LDS in the T-loop).
//  - 16 lanes (one DPP row) per batch element; 4 elements per wave.
//  - lane j holds h unit j; units 16..19 are computed by lanes 0..3 and
//    replicated across the row each step via bank-masked row_ror movs.
//  - The 20-wide dot product is computed with row_ror:r rotation FMAs
//    (units 0..15) + quad_perm broadcast FMAs (units 16..19).
//  - Wall = T * per-step chain; DPP keeps the chain in the VALU pipe
//    (~4 cyc/hop) instead of the ~200+ cyc LDS write->read round trip.
//
// DPP convention (per GCN3 ISA + the canonical row_shr scan idiom):
//   row_ror:r  => dest lane i receives src lane ((i - r) & 15)
//   quad_perm:[c,c,c,c] (ctrl = c*0x55) => every lane of a quad reads the
//   quad's lane c.

constexpr int Tn  = 2048;
constexpr int Hn  = 20;
constexpr int EPB = 16;   // elements per 256-thread block (one per 16-lane row)

__device__ __forceinline__ float tanh_fast(float s) {
    // tanh(s) = 1 - 2/(exp(2s)+1); exp2/rcp are ~1 ulp, fine vs 1.79e-2 thr.
    float e = __builtin_amdgcn_exp2f(s * 2.88539008177792681472f);
    float r = __builtin_amdgcn_rcpf(e + 1.0f);
    return __builtin_fmaf(-2.0f, r, 1.0f);
}

template <int CTRL, int ROWM, int BANKM>
__device__ __forceinline__ float dppf(float oldv, float src) {
    int r = __builtin_amdgcn_update_dpp(
        __builtin_bit_cast(int, oldv), __builtin_bit_cast(int, src),
        CTRL, ROWM, BANKM, false);
    return __builtin_bit_cast(float, r);
}

// Replicate lanes 0..3 of a row into lanes 4..15 (quad0 -> quads 1,2,3).
__device__ __forceinline__ float replicate_quad0(float v) {
    v = dppf<0x124, 0xF, 0x2>(v, v);   // row_ror:4  -> lanes 4..7   <- 0..3
    v = dppf<0x128, 0xF, 0x4>(v, v);   // row_ror:8  -> lanes 8..11  <- 0..3
    v = dppf<0x12C, 0xF, 0x8>(v, v);   // row_ror:12 -> lanes 12..15 <- 0..3
    return v;
}

__global__ __launch_bounds__(256, 1) void rnn_fwd(
    const float* __restrict__ x,     // [B, T, 4]
    const float* __restrict__ h0,    // [B, 20]
    const float* __restrict__ W_ih,  // [20, 4]
    const float* __restrict__ W_hh,  // [20, 20]
    const float* __restrict__ b_ih,  // [20]
    const float* __restrict__ b_hh,  // [20]
    const float* __restrict__ fc_w,  // [4, 20]
    const float* __restrict__ fc_b,  // [4]
    float* __restrict__ out)         // [B, 4]
{
    const int tid  = threadIdx.x;
    const int j    = tid & 15;            // lane within row = hidden unit
    const int e    = tid >> 4;            // element slot in block (0..15)
    const int b    = blockIdx.x * EPB + e;
    const bool hasB = (j < 4);
    const int  uB   = 16 + j;             // second output unit (real if j<4)

    // ---- per-lane weights, pre-permuted for the rotation schedule ----
    float wA[16], wB[16];                 // rotation weights for units 0..15
#pragma unroll
    for (int r = 0; r < 16; ++r) {
        const int k = (j - r) & 15;       // unit delivered by row_ror:r
        wA[r] = W_hh[j * Hn + k];
        wB[r] = hasB ? W_hh[uB * Hn + k] : 0.0f;
    }
    float wAq[4], wBq[4];                 // quad-broadcast weights, units 16..19
#pragma unroll
    for (int c = 0; c < 4; ++c) {
        wAq[c] = W_hh[j * Hn + 16 + c];
        wBq[c] = hasB ? W_hh[uB * Hn + 16 + c] : 0.0f;
    }
    float xiA[4], xiB[4];
#pragma unroll
    for (int i = 0; i < 4; ++i) {
        xiA[i] = W_ih[j * 4 + i];
        xiB[i] = hasB ? W_ih[uB * 4 + i] : 0.0f;
    }
    float biasA = b_ih[j] + b_hh[j];
    float biasB = hasB ? (b_ih[uB] + b_hh[uB]) : 0.0f;

    // Pin everything in VGPRs: round-1's VGPR_Count=36 showed the compiler
    // rematerializing loop-invariant weight loads INSIDE the step loop,
    // which put VMEM latency on the serial recurrence chain.
#pragma unroll
    for (int r = 0; r < 16; ++r) asm volatile("" : "+v"(wA[r]), "+v"(wB[r]));
#pragma unroll
    for (int c = 0; c < 4; ++c)
        asm volatile("" : "+v"(wAq[c]), "+v"(wBq[c]), "+v"(xiA[c]), "+v"(xiB[c]));
    asm volatile("" : "+v"(biasA), "+v"(biasB));

    // ---- initial state ----
    float hA  = h0[b * Hn + j];                       // unit j
    float hBr = hasB ? h0[b * Hn + uB] : 0.0f;        // unit 16+j in lanes 0..3
    hBr = replicate_quad0(hBr);                       // now h_{16+(j&3)} in all lanes

    const float4* __restrict__ xp =
        reinterpret_cast<const float4*>(x) + (size_t)b * Tn;

    auto step = [&](float4 xv) {
        // xi + bias, 2 chains per output
        float a0 = __builtin_fmaf(xv.x, xiA[0], biasA);
        float a1 = xv.y * xiA[1];
        a0 = __builtin_fmaf(xv.z, xiA[2], a0);
        a1 = __builtin_fmaf(xv.w, xiA[3], a1);
        float c0 = __builtin_fmaf(xv.x, xiB[0], biasB);
        float c1 = xv.y * xiB[1];
        c0 = __builtin_fmaf(xv.z, xiB[2], c0);
        c1 = __builtin_fmaf(xv.w, xiB[3], c1);

        // r = 0: own value, no rotation
        a0 = __builtin_fmaf(hA, wA[0], a0);
        c0 = __builtin_fmaf(hA, wB[0], c0);

        // r = 1..15: row_ror rotation FMAs (units 0..15)
#define ROT(R, AA, CC)                                                \
        {                                                             \
            float rv = dppf<0x120 + R, 0xF, 0xF>(hA, hA);             \
            AA = __builtin_fmaf(rv, wA[R], AA);                       \
            CC = __builtin_fmaf(rv, wB[R], CC);                       \
        }
        ROT(1,  a1, c1) ROT(2,  a0, c0) ROT(3,  a1, c1) ROT(4,  a0, c0)
        ROT(5,  a1, c1) ROT(6,  a0, c0) ROT(7,  a1, c1) ROT(8,  a0, c0)
        ROT(9,  a1, c1) ROT(10, a0, c0) ROT(11, a1, c1) ROT(12, a0, c0)
        ROT(13, a1, c1) ROT(14, a0, c0) ROT(15, a1, c1)
#undef ROT

        // units 16..19 via quad_perm broadcast of the replicated register
#define QB(C, CTRL, AA, CC)                                           \
        {                                                             \
            float qv = dppf<CTRL, 0xF, 0xF>(hBr, hBr);                \
            AA = __builtin_fmaf(qv, wAq[C], AA);                      \
            CC = __builtin_fmaf(qv, wBq[C], CC);                      \
        }
        QB(0, 0x00, a0, c0) QB(1, 0x55, a1, c1)
        QB(2, 0xAA, a0, c0) QB(3, 0xFF, a1, c1)
#undef QB

        float sA = a0 + a1;
        float sB = c0 + c1;
        hA = tanh_fast(sA);
        float hBn = tanh_fast(sB);        // lanes 0..3 real; others tanh(0)=0
        hBr = replicate_quad0(hBn);       // broadcast new h16..19 across row
    };

    // x prefetched 8 steps ahead in registers (~8 * ~170 cyc slack covers
    // L3/HBM latency off the recurrence chain).
    float4 cur0 = xp[0], cur1 = xp[1], cur2 = xp[2], cur3 = xp[3];
    float4 cur4 = xp[4], cur5 = xp[5], cur6 = xp[6], cur7 = xp[7];
#pragma unroll 1
    for (int t = 0; t < Tn; t += 8) {
        const int tp = (t + 8 < Tn) ? (t + 8) : (Tn - 8);  // tail reload, in-bounds
        float4 n0 = xp[tp + 0], n1 = xp[tp + 1], n2 = xp[tp + 2], n3 = xp[tp + 3];
        float4 n4 = xp[tp + 4], n5 = xp[tp + 5], n6 = xp[tp + 6], n7 = xp[tp + 7];
        step(cur0); step(cur1); step(cur2); step(cur3);
        step(cur4); step(cur5); step(cur6); step(cur7);
        cur0 = n0; cur1 = n1; cur2 = n2; cur3 = n3;
        cur4 = n4; cur5 = n5; cur6 = n6; cur7 = n7;
    }

    // ---- epilogue: out[b][m] = fc_b[m] + sum_k h[k] * fc_w[m][k] ----
    // Intra-wave LDS round trip (writes and reads by the same wave -> the
    // in-order DS pipe needs no barrier; round-1 validated this).
    __shared__ float sh[EPB][24];
    sh[e][j] = hA;
    if (hasB) sh[e][16 + j] = hBr;        // lanes 0..3 hold h16..19
    if (hasB) {
        float o = fc_b[j];
#pragma unroll
        for (int k = 0; k < Hn; ++k)
            o = __builtin_fmaf(sh[e][k], fc_w[j * Hn + k], o);
        out[b * 4 + j] = o;
    }
}

extern "C" void kernel_launch(void* const* d_in, const int* in_sizes, int n_in,
                              void* d_out, int out_size, void* d_ws, size_t ws_size,
                              hipStream_t stream) {
    const float* x    = (const float*)d_in[0];
    const float* h0   = (const float*)d_in[1];
    const float* W_ih = (const float*)d_in[2];
    const float* W_hh = (const float*)d_in[3];
    const float* b_ih = (const float*)d_in[4];
    const float* b_hh = (const float*)d_in[5];
    const float* fc_w = (const float*)d_in[6];
    const float* fc_b = (const float*)d_in[7];
    float* out = (float*)d_out;

    // 4096 elements / 16 per block = 256 blocks = 1024 waves = 1 wave/SIMD.
    rnn_fwd<<<dim3(256), dim3(256), 0, stream>>>(x, h0, W_ih, W_hh, b_ih, b_hh,
                                                 fc_w, fc_b, out);
}

// Round 3
// 473.923 us; speedup vs baseline: 1.1740x; 1.1740x over previous
//
#include <hip/hip_runtime.h>
#include <cstddef>

// Vanilla tanh-RNN: B=4096, T=2048, I=4, H=20, then Linear(20->4) on h_last.
//
// Round-3 design: DPP recurrence (round 2) + wave-local LDS double-buffered
// x staging (replaces round 2's 64-VGPR register prefetch, which the
// allocator stashed into AGPRs -> ~2x VALU instruction inflation,
// VGPR_Count=64, 439 us).
//
//  - 16 lanes (one DPP row) per batch element; 4 elements per wave;
//    4096 elem / 4 = 1024 waves = 1 wave/SIMD. Issue-bound regime.
//  - Recurrent dot product: row_ror:r DPP rotation FMAs (units 0..15) +
//    quad_perm broadcast FMAs (units 16..19). No LDS in the recurrence.
//  - x staging: per 16-step block, lane j loads x[b][t0+16+j] (one float4,
//    256 B contiguous per element) at block TOP, parks it in 4 VGPRs for
//    ~14 steps (hides HBM/L2 latency), then ds_write_b128 to the alternate
//    buffer. Steps consume via broadcast ds_read_b128 with a 2-step
//    register lookahead (q0,q1) so DS latency stays off the serial chain.
//  - Zero barriers: all LDS producer/consumer pairs are within one wave;
//    the DS pipe executes a wave's ops in program order (validated r1/r2).
//  - Element stride padded to 17 float4 (272 B) so the 4 broadcast rows a
//    wave reads per step hit different banks (256 B stride = 4-way conflict).

constexpr int Tn   = 2048;
constexpr int Hn   = 20;
constexpr int EPB  = 16;   // elements per 256-thread block
constexpr int SB   = 16;   // steps per staging block
constexpr int NBLK = Tn / SB;

__device__ __forceinline__ float tanh_fast(float s) {
    // tanh(s) = 1 - 2/(exp(2s)+1); exp2/rcp ~1 ulp, fine vs 1.79e-2 thr.
    float e = __builtin_amdgcn_exp2f(s * 2.88539008177792681472f);
    float r = __builtin_amdgcn_rcpf(e + 1.0f);
    return __builtin_fmaf(-2.0f, r, 1.0f);
}

template <int CTRL, int ROWM, int BANKM>
__device__ __forceinline__ float dppf(float oldv, float src) {
    int r = __builtin_amdgcn_update_dpp(
        __builtin_bit_cast(int, oldv), __builtin_bit_cast(int, src),
        CTRL, ROWM, BANKM, false);
    return __builtin_bit_cast(float, r);
}

// Replicate lanes 0..3 of a row into lanes 4..15 (quad0 -> quads 1,2,3).
__device__ __forceinline__ float replicate_quad0(float v) {
    v = dppf<0x124, 0xF, 0x2>(v, v);   // row_ror:4  -> lanes 4..7
    v = dppf<0x128, 0xF, 0x4>(v, v);   // row_ror:8  -> lanes 8..11
    v = dppf<0x12C, 0xF, 0x8>(v, v);   // row_ror:12 -> lanes 12..15
    return v;
}

__global__ __launch_bounds__(256, 1) void rnn_fwd(
    const float* __restrict__ x,     // [B, T, 4]
    const float* __restrict__ h0,    // [B, 20]
    const float* __restrict__ W_ih,  // [20, 4]
    const float* __restrict__ W_hh,  // [20, 20]
    const float* __restrict__ b_ih,  // [20]
    const float* __restrict__ b_hh,  // [20]
    const float* __restrict__ fc_w,  // [4, 20]
    const float* __restrict__ fc_b,  // [4]
    float* __restrict__ out)         // [B, 4]
{
    // [buf][elem][row(+1 pad)] ; elem stride 272 B breaks the 4-way bank
    // alias between the 4 elements a wave broadcasts from each step.
    __shared__ __align__(16) float4 xlds[2][EPB][SB + 1];
    __shared__ float hsh[EPB][24];

    const int tid  = threadIdx.x;
    const int j    = tid & 15;            // lane within row = hidden unit
    const int e    = tid >> 4;            // element slot in block (0..15)
    const int b    = blockIdx.x * EPB + e;
    const bool hasB = (j < 4);
    const int  uB   = 16 + j;             // second output unit (real if j<4)

    // ---- per-lane weights, pre-permuted for the rotation schedule ----
    float wA[16], wB[16];
#pragma unroll
    for (int r = 0; r < 16; ++r) {
        const int k = (j - r) & 15;       // unit delivered by row_ror:r
        wA[r] = W_hh[j * Hn + k];
        wB[r] = hasB ? W_hh[uB * Hn + k] : 0.0f;
    }
    float wAq[4], wBq[4];
#pragma unroll
    for (int c = 0; c < 4; ++c) {
        wAq[c] = W_hh[j * Hn + 16 + c];
        wBq[c] = hasB ? W_hh[uB * Hn + 16 + c] : 0.0f;
    }
    float xiA[4], xiB[4];
#pragma unroll
    for (int i = 0; i < 4; ++i) {
        xiA[i] = W_ih[j * 4 + i];
        xiB[i] = hasB ? W_ih[uB * 4 + i] : 0.0f;
    }
    float biasA = b_ih[j] + b_hh[j];
    float biasB = hasB ? (b_ih[uB] + b_hh[uB]) : 0.0f;

    // Keep weights in arch VGPRs (total demand ~80 regs now, so the
    // allocator has no pressure reason to stash them in AGPRs).
#pragma unroll
    for (int r = 0; r < 16; ++r) asm volatile("" : "+v"(wA[r]), "+v"(wB[r]));
#pragma unroll
    for (int c = 0; c < 4; ++c)
        asm volatile("" : "+v"(wAq[c]), "+v"(wBq[c]), "+v"(xiA[c]), "+v"(xiB[c]));
    asm volatile("" : "+v"(biasA), "+v"(biasB));

    // ---- initial state ----
    float hA  = h0[b * Hn + j];
    float hBr = hasB ? h0[b * Hn + uB] : 0.0f;
    hBr = replicate_quad0(hBr);           // h_{16+(lane&3)} in all lanes

    const float4* __restrict__ xp =
        reinterpret_cast<const float4*>(x) + (size_t)b * Tn;

    auto step = [&](float4 xv) {
        float a0 = __builtin_fmaf(xv.x, xiA[0], biasA);
        float a1 = xv.y * xiA[1];
        a0 = __builtin_fmaf(xv.z, xiA[2], a0);
        a1 = __builtin_fmaf(xv.w, xiA[3], a1);
        float c0 = __builtin_fmaf(xv.x, xiB[0], biasB);
        float c1 = xv.y * xiB[1];
        c0 = __builtin_fmaf(xv.z, xiB[2], c0);
        c1 = __builtin_fmaf(xv.w, xiB[3], c1);

        a0 = __builtin_fmaf(hA, wA[0], a0);
        c0 = __builtin_fmaf(hA, wB[0], c0);

#define ROT(R, AA, CC)                                                \
        {                                                             \
            float rv = dppf<0x120 + R, 0xF, 0xF>(hA, hA);             \
            AA = __builtin_fmaf(rv, wA[R], AA);                       \
            CC = __builtin_fmaf(rv, wB[R], CC);                       \
        }
        ROT(1,  a1, c1) ROT(2,  a0, c0) ROT(3,  a1, c1) ROT(4,  a0, c0)
        ROT(5,  a1, c1) ROT(6,  a0, c0) ROT(7,  a1, c1) ROT(8,  a0, c0)
        ROT(9,  a1, c1) ROT(10, a0, c0) ROT(11, a1, c1) ROT(12, a0, c0)
        ROT(13, a1, c1) ROT(14, a0, c0) ROT(15, a1, c1)
#undef ROT

#define QB(C, CTRL, AA, CC)                                           \
        {                                                             \
            float qv = dppf<CTRL, 0xF, 0xF>(hBr, hBr);                \
            AA = __builtin_fmaf(qv, wAq[C], AA);                      \
            CC = __builtin_fmaf(qv, wBq[C], CC);                      \
        }
        QB(0, 0x00, a0, c0) QB(1, 0x55, a1, c1)
        QB(2, 0xAA, a0, c0) QB(3, 0xFF, a1, c1)
#undef QB

        float sA = a0 + a1;
        float sB = c0 + c1;
        hA = tanh_fast(sA);
        float hBn = tanh_fast(sB);        // lanes 0..3 real; others tanh(0)=0
        hBr = replicate_quad0(hBn);
    };

    // ---- prologue: stage steps 0..15 into buffer 0, prime 2-deep queue ----
    xlds[0][e][j] = xp[j];                // lane j -> row j (coalesced load)
    float4 q0 = xlds[0][e][0];
    float4 q1 = xlds[0][e][1];

    int cur = 0;
#pragma unroll 1
    for (int k = 0; k < NBLK; ++k) {
        const int kn = (k + 1 < NBLK) ? (k + 1) : (NBLK - 1);  // tail: reload last block
        float4 xr = xp[kn * SB + j];      // global load at block TOP: ~14 steps
                                          // of slack before its ds_write
        const int nxt = cur ^ 1;
#pragma unroll
        for (int s = 0; s < SB - 2; ++s) {
            float4 xv = q0; q0 = q1;
            q1 = xlds[cur][e][s + 2];     // 2-step LDS lookahead
            step(xv);
        }
        xlds[nxt][e][j] = xr;             // all prior reads of nxt already issued
        { float4 xv = q0; q0 = q1; q1 = xlds[nxt][e][0]; step(xv); }   // s=14
        { float4 xv = q0; q0 = q1; q1 = xlds[nxt][e][1]; step(xv); }   // s=15
        cur = nxt;
    }

    // ---- epilogue: out[b][m] = fc_b[m] + sum_k h[k] * fc_w[m][k] ----
    hsh[e][j] = hA;
    if (hasB) hsh[e][16 + j] = hBr;       // lanes 0..3 hold h16..19
    if (hasB) {
        float o = fc_b[j];
#pragma unroll
        for (int k = 0; k < Hn; ++k)
            o = __builtin_fmaf(hsh[e][k], fc_w[j * Hn + k], o);
        out[b * 4 + j] = o;
    }
}

extern "C" void kernel_launch(void* const* d_in, const int* in_sizes, int n_in,
                              void* d_out, int out_size, void* d_ws, size_t ws_size,
                              hipStream_t stream) {
    const float* x    = (const float*)d_in[0];
    const float* h0   = (const float*)d_in[1];
    const float* W_ih = (const float*)d_in[2];
    const float* W_hh = (const float*)d_in[3];
    const float* b_ih = (const float*)d_in[4];
    const float* b_hh = (const float*)d_in[5];
    const float* fc_w = (const float*)d_in[6];
    const float* fc_b = (const float*)d_in[7];
    float* out = (float*)d_out;

    // 4096 elements / 16 per block = 256 blocks = 1024 waves = 1 wave/SIMD.
    rnn_fwd<<<dim3(256), dim3(256), 0, stream>>>(x, h0, W_ih, W_hh, b_ih, b_hh,
                                                 fc_w, fc_b, out);
}

// Round 4
// 473.918 us; speedup vs baseline: 1.1740x; 1.0000x over previous
//
#include <hip/hip_runtime.h>
#include <cstddef>

// Vanilla tanh-RNN: B=4096, T=2048, I=4, H=20, then Linear(20->4) on h_last.
//
// Round-4 design: phase-separated DPP step for intra-wave ILP.
//
// Cross-round evidence (R1-R3): every design ran at ~4 cyc/VALU-inst, not
// the 2-cyc wave64 issue rate -> at 1 wave/SIMD the SIMD pays dependent
// latency because consecutive instructions are dependent (mov rv; fma(rv..)
// pairs). Fix: batch ALL cross-lane movs (independent of each other), then
// ALL FMAs (operands ready, 4 round-robin chains), with sched_barrier(0)
// fences so the compiler cannot re-interleave them into dependent pairs.
//
// Also new vs R3: "all-lanes-B" — every lane accumulates the full dot
// product for unit 16+(j&3) via the same rv sweep (rv_r = h_{(j-r)&15}
// covers all 16 units), so tanh(cB) lands already-replicated: no
// replicate_quad0, no wasted B-side FMA lanes, shorter B chain.
//
//  - 16 lanes (one DPP row) per element; 4 elements/wave; 1024 waves
//    = 1 wave/SIMD (4096 elements is the total parallelism).
//  - x staged through a wave-local LDS double buffer (R3), 3-step register
//    lookahead; zero barriers (intra-wave DS program order, validated R1-R3).

constexpr int Tn   = 2048;
constexpr int Hn   = 20;
constexpr int EPB  = 16;   // elements per 256-thread block
constexpr int SB   = 16;   // steps per staging block
constexpr int NBLK = Tn / SB;

template <int CTRL, int ROWM, int BANKM>
__device__ __forceinline__ float dppf(float oldv, float src) {
    int r = __builtin_amdgcn_update_dpp(
        __builtin_bit_cast(int, oldv), __builtin_bit_cast(int, src),
        CTRL, ROWM, BANKM, false);
    return __builtin_bit_cast(float, r);
}

__global__ __launch_bounds__(256, 1) void rnn_fwd(
    const float* __restrict__ x,     // [B, T, 4]
    const float* __restrict__ h0,    // [B, 20]
    const float* __restrict__ W_ih,  // [20, 4]
    const float* __restrict__ W_hh,  // [20, 20]
    const float* __restrict__ b_ih,  // [20]
    const float* __restrict__ b_hh,  // [20]
    const float* __restrict__ fc_w,  // [4, 20]
    const float* __restrict__ fc_b,  // [4]
    float* __restrict__ out)         // [B, 4]
{
    // [buf][elem][row(+1 pad)] ; 272 B elem stride de-aliases the 4 element
    // rows a wave broadcasts from each step.
    __shared__ __align__(16) float4 xlds[2][EPB][SB + 1];
    __shared__ float hsh[EPB][24];

    const int tid = threadIdx.x;
    const int j   = tid & 15;             // lane within row = A-unit index
    const int e   = tid >> 4;             // element slot in block (0..15)
    const int b   = blockIdx.x * EPB + e;
    const int uB  = 16 + (j & 3);         // B-unit this lane accumulates

    // ---- per-lane weights (rotation-permuted) ----
    float wA[16], wB[16];
#pragma unroll
    for (int r = 0; r < 16; ++r) {
        const int k = (j - r) & 15;       // unit delivered by row_ror:r
        wA[r] = W_hh[j  * Hn + k];
        wB[r] = W_hh[uB * Hn + k];
    }
    float wAq[4], wBq[4], xiA[4], xiB[4];
#pragma unroll
    for (int c = 0; c < 4; ++c) {
        wAq[c] = W_hh[j  * Hn + 16 + c];
        wBq[c] = W_hh[uB * Hn + 16 + c];
        xiA[c] = W_ih[j  * 4 + c];
        xiB[c] = W_ih[uB * 4 + c];
    }
    float biasA = b_ih[j]  + b_hh[j];
    float biasB = b_ih[uB] + b_hh[uB];

    // One-time pin so the weight loads stay out of the loop.
#pragma unroll
    for (int r = 0; r < 16; ++r) asm volatile("" : "+v"(wA[r]), "+v"(wB[r]));
#pragma unroll
    for (int c = 0; c < 4; ++c)
        asm volatile("" : "+v"(wAq[c]), "+v"(wBq[c]), "+v"(xiA[c]), "+v"(xiB[c]));
    asm volatile("" : "+v"(biasA), "+v"(biasB));

    // ---- initial state ----
    float hA  = h0[b * Hn + j];           // unit j
    float hBr = h0[b * Hn + uB];          // unit 16+(j&3), already "replicated"

    const float4* __restrict__ xp =
        reinterpret_cast<const float4*>(x) + (size_t)b * Tn;

    const float TWO_LOG2E = 2.88539008177792681472f;

    auto step = [&](float4 xv) {
        // ---- Phase 1: cross-lane movs, batched (mutually independent) ----
        float rv1  = dppf<0x121, 0xF, 0xF>(hA, hA);
        float rv2  = dppf<0x122, 0xF, 0xF>(hA, hA);
        float rv3  = dppf<0x123, 0xF, 0xF>(hA, hA);
        float rv4  = dppf<0x124, 0xF, 0xF>(hA, hA);
        float rv5  = dppf<0x125, 0xF, 0xF>(hA, hA);
        float rv6  = dppf<0x126, 0xF, 0xF>(hA, hA);
        float rv7  = dppf<0x127, 0xF, 0xF>(hA, hA);
        float rv8  = dppf<0x128, 0xF, 0xF>(hA, hA);
        float rv9  = dppf<0x129, 0xF, 0xF>(hA, hA);
        float rv10 = dppf<0x12A, 0xF, 0xF>(hA, hA);
        float rv11 = dppf<0x12B, 0xF, 0xF>(hA, hA);
        float rv12 = dppf<0x12C, 0xF, 0xF>(hA, hA);
        float rv13 = dppf<0x12D, 0xF, 0xF>(hA, hA);
        float rv14 = dppf<0x12E, 0xF, 0xF>(hA, hA);
        float rv15 = dppf<0x12F, 0xF, 0xF>(hA, hA);
        float qv0  = dppf<0x00,  0xF, 0xF>(hBr, hBr);  // quad_perm c=0
        float qv1  = dppf<0x55,  0xF, 0xF>(hBr, hBr);  // c=1
        float qv2  = dppf<0xAA,  0xF, 0xF>(hBr, hBr);  // c=2
        float qv3  = dppf<0xFF,  0xF, 0xF>(hBr, hBr);  // c=3
        __builtin_amdgcn_sched_barrier(0);

        // ---- Phase 2: FMA block, 4 round-robin chains (a0,c0,a1,c1) ----
        float a0 = __builtin_fmaf(xv.x, xiA[0], biasA);
        float c0 = __builtin_fmaf(xv.x, xiB[0], biasB);
        float a1 = xv.y * xiA[1];
        float c1 = xv.y * xiB[1];
        a0 = __builtin_fmaf(xv.z,  xiA[2], a0);
        c0 = __builtin_fmaf(xv.z,  xiB[2], c0);
        a1 = __builtin_fmaf(xv.w,  xiA[3], a1);
        c1 = __builtin_fmaf(xv.w,  xiB[3], c1);
        a0 = __builtin_fmaf(hA,   wA[0],  a0);
        c0 = __builtin_fmaf(hA,   wB[0],  c0);
        a1 = __builtin_fmaf(rv1,  wA[1],  a1);
        c1 = __builtin_fmaf(rv1,  wB[1],  c1);
        a0 = __builtin_fmaf(rv2,  wA[2],  a0);
        c0 = __builtin_fmaf(rv2,  wB[2],  c0);
        a1 = __builtin_fmaf(rv3,  wA[3],  a1);
        c1 = __builtin_fmaf(rv3,  wB[3],  c1);
        a0 = __builtin_fmaf(rv4,  wA[4],  a0);
        c0 = __builtin_fmaf(rv4,  wB[4],  c0);
        a1 = __builtin_fmaf(rv5,  wA[5],  a1);
        c1 = __builtin_fmaf(rv5,  wB[5],  c1);
        a0 = __builtin_fmaf(rv6,  wA[6],  a0);
        c0 = __builtin_fmaf(rv6,  wB[6],  c0);
        a1 = __builtin_fmaf(rv7,  wA[7],  a1);
        c1 = __builtin_fmaf(rv7,  wB[7],  c1);
        a0 = __builtin_fmaf(rv8,  wA[8],  a0);
        c0 = __builtin_fmaf(rv8,  wB[8],  c0);
        a1 = __builtin_fmaf(rv9,  wA[9],  a1);
        c1 = __builtin_fmaf(rv9,  wB[9],  c1);
        a0 = __builtin_fmaf(rv10, wA[10], a0);
        c0 = __builtin_fmaf(rv10, wB[10], c0);
        a1 = __builtin_fmaf(rv11, wA[11], a1);
        c1 = __builtin_fmaf(rv11, wB[11], c1);
        a0 = __builtin_fmaf(rv12, wA[12], a0);
        c0 = __builtin_fmaf(rv12, wB[12], c0);
        a1 = __builtin_fmaf(rv13, wA[13], a1);
        c1 = __builtin_fmaf(rv13, wB[13], c1);
        a0 = __builtin_fmaf(rv14, wA[14], a0);
        c0 = __builtin_fmaf(rv14, wB[14], c0);
        a1 = __builtin_fmaf(rv15, wA[15], a1);
        c1 = __builtin_fmaf(rv15, wB[15], c1);
        a0 = __builtin_fmaf(qv0,  wAq[0], a0);
        c0 = __builtin_fmaf(qv0,  wBq[0], c0);
        a1 = __builtin_fmaf(qv1,  wAq[1], a1);
        c1 = __builtin_fmaf(qv1,  wBq[1], c1);
        a0 = __builtin_fmaf(qv2,  wAq[2], a0);
        c0 = __builtin_fmaf(qv2,  wBq[2], c0);
        a1 = __builtin_fmaf(qv3,  wAq[3], a1);
        c1 = __builtin_fmaf(qv3,  wBq[3], c1);
        __builtin_amdgcn_sched_barrier(0);

        // ---- Phase 3: adds + two interleaved tanh chains ----
        float sA = a0 + a1;
        float sB = c0 + c1;
        float eA = __builtin_amdgcn_exp2f(sA * TWO_LOG2E);
        float eB = __builtin_amdgcn_exp2f(sB * TWO_LOG2E);
        float rA = __builtin_amdgcn_rcpf(eA + 1.0f);
        float rB = __builtin_amdgcn_rcpf(eB + 1.0f);
        hA  = __builtin_fmaf(-2.0f, rA, 1.0f);
        hBr = __builtin_fmaf(-2.0f, rB, 1.0f);
    };

    // ---- prologue: stage steps 0..15 into buffer 0, prime 3-deep queue ----
    xlds[0][e][j] = xp[j];                // lane j -> row j (coalesced)
    float4 q0 = xlds[0][e][0];
    float4 q1 = xlds[0][e][1];
    float4 q2 = xlds[0][e][2];

    int cur = 0;
#pragma unroll 1
    for (int k = 0; k < NBLK; ++k) {
        const int kn = (k + 1 < NBLK) ? (k + 1) : (NBLK - 1);  // tail reload
        float4 xr = xp[kn * SB + j];      // global load at block TOP
        const int nxt = cur ^ 1;
#pragma unroll
        for (int s = 0; s < SB - 3; ++s) {                     // s = 0..12
            float4 xv = q0; q0 = q1; q1 = q2;
            q2 = xlds[cur][e][s + 3];     // 3-step LDS lookahead
            step(xv);
        }
        xlds[nxt][e][j] = xr;             // prior reads of nxt already issued
        { float4 xv = q0; q0 = q1; q1 = q2; q2 = xlds[nxt][e][0]; step(xv); }
        { float4 xv = q0; q0 = q1; q1 = q2; q2 = xlds[nxt][e][1]; step(xv); }
        { float4 xv = q0; q0 = q1; q1 = q2; q2 = xlds[nxt][e][2]; step(xv); }
        cur = nxt;
    }

    // ---- epilogue: out[b][m] = fc_b[m] + sum_k h[k] * fc_w[m][k] ----
    hsh[e][j] = hA;                       // units 0..15
    if (j < 4) hsh[e][16 + j] = hBr;      // lane j holds unit 16+j for j<4
    if (j < 4) {
        float o = fc_b[j];
#pragma unroll
        for (int k = 0; k < Hn; ++k)
            o = __builtin_fmaf(hsh[e][k], fc_w[j * Hn + k], o);
        out[b * 4 + j] = o;
    }
}

extern "C" void kernel_launch(void* const* d_in, const int* in_sizes, int n_in,
                              void* d_out, int out_size, void* d_ws, size_t ws_size,
                              hipStream_t stream) {
    const float* x    = (const float*)d_in[0];
    const float* h0   = (const float*)d_in[1];
    const float* W_ih = (const float*)d_in[2];
    const float* W_hh = (const float*)d_in[3];
    const float* b_ih = (const float*)d_in[4];
    const float* b_hh = (const float*)d_in[5];
    const float* fc_w = (const float*)d_in[6];
    const float* fc_b = (const float*)d_in[7];
    float* out = (float*)d_out;

    // 4096 elements / 16 per block = 256 blocks = 1024 waves = 1 wave/SIMD.
    rnn_fwd<<<dim3(256), dim3(256), 0, stream>>>(x, h0, W_ih, W_hh, b_ih, b_hh,
                                                 fc_w, fc_b, out);
}